// Round 9
// baseline (882.350 us; speedup 1.0000x reference)
//
#include <hip/hip_runtime.h>
#include <math.h>

namespace {

constexpr int D    = 49;
constexpr int H    = 8;
constexpr int L    = 4;
constexpr int HID  = 25;
constexpr int NCLS = 10;
constexpr int XS   = 68;    // LDS staging row stride (bf16 elems)
constexpr int WSM  = 4096;  // ushorts per padded 64x64 matrix in frag layout
constexpr float NEGBIG = -1e30f;
// fold 1/(sqrt(49)+1e-6) * log2(e) into Wk so softmax uses exp2 directly
constexpr float SCLF  = 1.44269504088896f / (7.0f + 1e-6f);
constexpr float CLIP2 = 30.0f * 1.44269504088896f;  // clip bounds in log2 domain

typedef __attribute__((ext_vector_type(4))) short short4v;
typedef __attribute__((ext_vector_type(8))) short short8v;
typedef __attribute__((ext_vector_type(4))) float float4v;
typedef __attribute__((ext_vector_type(8))) __bf16 bf16x8;

__device__ __forceinline__ float4v mfma32(short8v a, short8v b, float4v c) {
  return __builtin_amdgcn_mfma_f32_16x16x32_bf16(a, b, c, 0, 0, 0);
}

__device__ __forceinline__ unsigned short f2bf(float x) {  // RNE
  unsigned u = __float_as_uint(x);
  return (unsigned short)((u + 0x7FFFu + ((u >> 16) & 1u)) >> 16);
}

__device__ __forceinline__ short8v cvt8(float4v lo, float4v hi) {
  bf16x8 b = {(__bf16)lo[0], (__bf16)lo[1], (__bf16)lo[2], (__bf16)lo[3],
              (__bf16)hi[0], (__bf16)hi[1], (__bf16)hi[2], (__bf16)hi[3]};
  return __builtin_bit_cast(short8v, b);
}

__device__ __forceinline__ unsigned pk2(float a, float b) {  // 2xf32 -> packed bf16
  union { __bf16 h[2]; unsigned u; } q;
  q.h[0] = (__bf16)a; q.h[1] = (__bf16)b;
  return q.u;
}
__device__ __forceinline__ float bflo(unsigned u) { return __uint_as_float(u << 16); }
__device__ __forceinline__ float bfhi(unsigned u) { return __uint_as_float(u & 0xFFFF0000u); }

__device__ __forceinline__ float4v splat4(float x) {
  float4v v; v[0] = x; v[1] = x; v[2] = x; v[3] = x; return v;
}

__device__ __forceinline__ short8v wsld8(const unsigned short* __restrict__ w,
                                         int t, int nt, int lane) {
  return *reinterpret_cast<const short8v*>(w + ((t * 4 + nt) * 64 + lane) * 8);
}

__device__ __forceinline__ float4v rowbias(const float* __restrict__ bp, int mt, int g) {
  float4v r;
  #pragma unroll
  for (int i = 0; i < 4; ++i) {
    const int e = 16 * mt + 4 * g + i;
    r[i] = (e < D) ? bp[e] : 0.0f;
  }
  return r;
}

// acc(cfrag of OUT^T) = W^T @ SRC + bscale*rowbias
__device__ __forceinline__ void mmT8(const unsigned short* __restrict__ w,
                                     const short8v (&src)[2][4],
                                     const float* __restrict__ bp, float bscale,
                                     int g, int lane, float4v (&acc)[4][4]) {
  #pragma unroll
  for (int mt = 0; mt < 4; ++mt) {
    const float4v rb = rowbias(bp, mt, g) * bscale;
    #pragma unroll
    for (int nt = 0; nt < 4; ++nt) acc[mt][nt] = rb;
  }
  #pragma unroll
  for (int t = 0; t < 2; ++t) {
    short8v a[4];
    #pragma unroll
    for (int mt = 0; mt < 4; ++mt) a[mt] = wsld8(w, t, mt, lane);
    #pragma unroll
    for (int nt = 0; nt < 4; ++nt)
      #pragma unroll
      for (int mt = 0; mt < 4; ++mt)
        acc[mt][nt] = mfma32(a[mt], src[t][nt], acc[mt][nt]);
  }
}

// Pre-shuffle 49x49 f32 -> padded 64x64 bf16, K=32-native frag layout.
// Wk (m in [32,64)) is pre-scaled by SCLF.
__global__ void __launch_bounds__(256)
prep_weights(const float* __restrict__ Wq, const float* __restrict__ Wk,
             const float* __restrict__ Wv, const float* __restrict__ Wh,
             const float* __restrict__ Wout, const float* __restrict__ W1,
             const float* __restrict__ W2, unsigned short* __restrict__ ws) {
  const int m = blockIdx.x;  // 0..167
  const float* src;
  float scl = 1.0f;
  if (m < 32)       src = Wq   + (size_t)m * D * D;
  else if (m < 64)  { src = Wk + (size_t)(m - 32) * D * D; scl = SCLF; }
  else if (m < 96)  src = Wv   + (size_t)(m - 64) * D * D;
  else if (m < 128) src = Wh   + (size_t)(m - 96) * D * D;
  else if (m < 160) src = Wout + (size_t)(m - 128) * D * D;
  else if (m < 164) src = W1   + (size_t)(m - 160) * D * D;
  else              src = W2   + (size_t)(m - 164) * D * D;

  const int tid = threadIdx.x;
  const int lane = tid & 63;
  const int gg = (lane >> 4) & 3, cc = lane & 15;
  #pragma unroll
  for (int i = 0; i < 2; ++i) {
    const int p = ((tid >> 6) << 1) | i;  // 0..7
    const int tt = p >> 2, nt = p & 3;
    short8v v;
    #pragma unroll
    for (int j = 0; j < 8; ++j) {
      const int k = 32 * tt + ((j < 4) ? (4 * gg + j) : (16 + 4 * gg + j - 4));
      const int n = 16 * nt + cc;
      const float f = (k < D && n < D) ? src[k * D + n] * scl : 0.0f;
      v[j] = (short)f2bf(f);
    }
    *reinterpret_cast<short8v*>(ws + (size_t)m * WSM + ((tt * 4 + nt) * 64 + lane) * 8) = v;
  }
}

// block = 2 waves, 1 item; wave w handles heads 4w..4w+3; od exchanged via LDS.
__global__ void __launch_bounds__(128, 4)
encoder_kernel(const float* __restrict__ emb, const int* __restrict__ labels,
               const unsigned short* __restrict__ ws,
               const float* __restrict__ bq, const float* __restrict__ bk,
               const float* __restrict__ bv, const float* __restrict__ bh,
               const float* __restrict__ b1, const float* __restrict__ b2,
               const float* __restrict__ Wc1, const float* __restrict__ bc1,
               const float* __restrict__ Wc2, const float* __restrict__ bc2,
               float* __restrict__ ws_loss, float* __restrict__ ws_corr) {
  __shared__ unsigned EX[2][2048];  // 16 KB: od exchange; aliased for X staging
  __shared__ float CLS[128];

  const int b = blockIdx.x;
  const int tid = threadIdx.x;
  const int w = tid >> 6;            // wave id 0/1
  const int lane = tid & 63;
  const int g = lane >> 4, c = lane & 15;

  // ---- stage embedding (zero-padded 64x64 bf16) into aliased LDS ----
  unsigned short* Xs = reinterpret_cast<unsigned short*>(&EX[0][0]);
  for (int idx = tid; idx < 64 * 64; idx += 128) {
    const int r = idx >> 6, cc = idx & 63;
    const float v = (r < D && cc < D) ? emb[(size_t)b * (D * D) + r * D + cc] : 0.0f;
    Xs[r * XS + cc] = f2bf(v);
  }
  __syncthreads();

  short8v xf8[2][4];  // operand frag of X (contraction over d)
  #pragma unroll
  for (int t = 0; t < 2; ++t)
    #pragma unroll
    for (int nt = 0; nt < 4; ++nt) {
      const int base = (16 * nt + c) * XS + 32 * t + 4 * g;
      short4v lo = *reinterpret_cast<const short4v*>(&Xs[base]);
      short4v hi = *reinterpret_cast<const short4v*>(&Xs[base + 16]);
      xf8[t][nt] = __builtin_shufflevector(lo, hi, 0, 1, 2, 3, 4, 5, 6, 7);
    }
  __syncthreads();  // X fully read before EX is reused for od exchange

  float4v xacc[4][4];  // cfrag(x^T)

  #pragma unroll 1
  for (int l = 0; l < L; ++l) {
    float4v od[4][4];  // partial od^T over this wave's 4 heads
    #pragma unroll
    for (int mt = 0; mt < 4; ++mt)
      #pragma unroll
      for (int nt = 0; nt < 4; ++nt) od[mt][nt] = splat4(0.0f);

    #pragma unroll 1
    for (int hh = 0; hh < 4; ++hh) {
      const int lh = l * H + 4 * w + hh;
      const unsigned short* wq = ws + (size_t)(0   + lh) * WSM;
      const unsigned short* wk = ws + (size_t)(32  + lh) * WSM;
      const unsigned short* wv = ws + (size_t)(64  + lh) * WSM;
      const unsigned short* wh = ws + (size_t)(96  + lh) * WSM;
      const unsigned short* wo = ws + (size_t)(128 + lh) * WSM;

      // ---- K^T (pre-scaled) then Q^T ----
      short8v kf8[2][4], qf8[2][4];
      {
        float4v ka[4][4];
        mmT8(wk, xf8, bk + lh * D, SCLF, g, lane, ka);
        #pragma unroll
        for (int t = 0; t < 2; ++t)
          #pragma unroll
          for (int nt = 0; nt < 4; ++nt)
            kf8[t][nt] = cvt8(ka[2 * t][nt], ka[2 * t + 1][nt]);
      }
      {
        float4v qa[4][4];
        mmT8(wq, xf8, bq + lh * D, 1.0f, g, lane, qa);
        #pragma unroll
        for (int t = 0; t < 2; ++t)
          #pragma unroll
          for (int nt = 0; nt < 4; ++nt)
            qf8[t][nt] = cvt8(qa[2 * t][nt], qa[2 * t + 1][nt]);
      }

      // ---- S^T = K @ Q^T (already in log2-softmax domain) ----
      float4v s[4][4];
      #pragma unroll
      for (int mt = 0; mt < 4; ++mt)
        #pragma unroll
        for (int nt = 0; nt < 4; ++nt) s[mt][nt] = splat4(0.0f);
      #pragma unroll
      for (int t = 0; t < 2; ++t)
        #pragma unroll
        for (int nt = 0; nt < 4; ++nt)
          #pragma unroll
          for (int mt = 0; mt < 4; ++mt)
            s[mt][nt] = mfma32(kf8[t][mt], qf8[t][nt], s[mt][nt]);

      // ---- clip (log2 domain), mask pad keys, softmax via exp2 ----
      #pragma unroll
      for (int mt = 0; mt < 4; ++mt)
        #pragma unroll
        for (int nt = 0; nt < 4; ++nt)
          #pragma unroll
          for (int r = 0; r < 4; ++r) {
            float sv = fminf(fmaxf(s[mt][nt][r], -CLIP2), CLIP2);
            if (mt == 3) sv = (r == 0 && g == 0) ? sv : NEGBIG;
            s[mt][nt][r] = sv;
          }
      float inv_[4];
      #pragma unroll
      for (int nt = 0; nt < 4; ++nt) {
        float mx = s[0][nt][0];
        #pragma unroll
        for (int mt = 0; mt < 4; ++mt)
          #pragma unroll
          for (int r = 0; r < 4; ++r) mx = fmaxf(mx, s[mt][nt][r]);
        mx = fmaxf(mx, __shfl_xor(mx, 16));
        mx = fmaxf(mx, __shfl_xor(mx, 32));
        float dn = 0.0f;
        #pragma unroll
        for (int mt = 0; mt < 4; ++mt)
          #pragma unroll
          for (int r = 0; r < 4; ++r) {
            const float p = exp2f(s[mt][nt][r] - mx);
            s[mt][nt][r] = p;
            dn += p;
          }
        dn += __shfl_xor(dn, 16);
        dn += __shfl_xor(dn, 32);
        inv_[nt] = 1.0f / fmaxf(dn, 1e-37f);
      }
      short8v pf8[2][4];
      #pragma unroll
      for (int t = 0; t < 2; ++t)
        #pragma unroll
        for (int nt = 0; nt < 4; ++nt)
          pf8[t][nt] = cvt8(s[2 * t][nt], s[2 * t + 1][nt]);

      // ---- V = X @ Wv + bv ----
      short8v vf8[2][4];
      {
        float4v va[4][4];
        #pragma unroll
        for (int nt = 0; nt < 4; ++nt) {
          const int e = 16 * nt + c;
          const float bvv = (e < D) ? bv[lh * D + e] : 0.0f;
          #pragma unroll
          for (int mt = 0; mt < 4; ++mt) va[mt][nt] = splat4(bvv);
        }
        #pragma unroll
        for (int t = 0; t < 2; ++t) {
          short8v wvf[4];
          #pragma unroll
          for (int nt = 0; nt < 4; ++nt) wvf[nt] = wsld8(wv, t, nt, lane);
          #pragma unroll
          for (int nt = 0; nt < 4; ++nt)
            #pragma unroll
            for (int mt = 0; mt < 4; ++mt)
              va[mt][nt] = mfma32(xf8[t][mt], wvf[nt], va[mt][nt]);
        }
        #pragma unroll
        for (int t = 0; t < 2; ++t)
          #pragma unroll
          for (int nt = 0; nt < 4; ++nt)
            vf8[t][nt] = cvt8(va[2 * t][nt], va[2 * t + 1][nt]);
      }

      // ---- ctx^T = V^T @ P^T, * inv_den per query col ----
      short8v cf8[2][4];
      {
        float4v ca[4][4];
        #pragma unroll
        for (int mt = 0; mt < 4; ++mt)
          #pragma unroll
          for (int nt = 0; nt < 4; ++nt) ca[mt][nt] = splat4(0.0f);
        #pragma unroll
        for (int t = 0; t < 2; ++t)
          #pragma unroll
          for (int nt = 0; nt < 4; ++nt)
            #pragma unroll
            for (int mt = 0; mt < 4; ++mt)
              ca[mt][nt] = mfma32(vf8[t][mt], pf8[t][nt], ca[mt][nt]);
        #pragma unroll
        for (int t = 0; t < 2; ++t)
          #pragma unroll
          for (int nt = 0; nt < 4; ++nt)
            cf8[t][nt] = cvt8(ca[2 * t][nt] * inv_[nt], ca[2 * t + 1][nt] * inv_[nt]);
      }

      // ---- ho^T = Wh^T @ ctx^T + bh ----
      short8v hf8[2][4];
      {
        float4v ha[4][4];
        mmT8(wh, cf8, bh + lh * D, 1.0f, g, lane, ha);
        #pragma unroll
        for (int t = 0; t < 2; ++t)
          #pragma unroll
          for (int nt = 0; nt < 4; ++nt)
            hf8[t][nt] = cvt8(ha[2 * t][nt], ha[2 * t + 1][nt]);
      }

      // ---- od^T += Wout^T @ ho^T ----
      #pragma unroll
      for (int t = 0; t < 2; ++t) {
        short8v a[4];
        #pragma unroll
        for (int mt = 0; mt < 4; ++mt) a[mt] = wsld8(wo, t, mt, lane);
        #pragma unroll
        for (int nt = 0; nt < 4; ++nt)
          #pragma unroll
          for (int mt = 0; mt < 4; ++mt)
            od[mt][nt] = mfma32(a[mt], hf8[t][nt], od[mt][nt]);
      }
    }  // heads (this wave's 4)

    // ---- cross-wave od exchange (bf16) ----
    #pragma unroll
    for (int mt = 0; mt < 4; ++mt)
      #pragma unroll
      for (int nt = 0; nt < 4; ++nt) {
        uint2 v;
        v.x = pk2(od[mt][nt][0], od[mt][nt][1]);
        v.y = pk2(od[mt][nt][2], od[mt][nt][3]);
        *reinterpret_cast<uint2*>(&EX[w][(mt * 4 + nt) * 128 + lane * 2]) = v;
      }
    __syncthreads();
    #pragma unroll
    for (int mt = 0; mt < 4; ++mt)
      #pragma unroll
      for (int nt = 0; nt < 4; ++nt) {
        const uint2 v = *reinterpret_cast<const uint2*>(
            &EX[1 - w][(mt * 4 + nt) * 128 + lane * 2]);
        od[mt][nt][0] += bflo(v.x);
        od[mt][nt][1] += bfhi(v.x);
        od[mt][nt][2] += bflo(v.y);
        od[mt][nt][3] += bfhi(v.y);
      }
    __syncthreads();  // buffers free for next layer

    // ---- MLP (both waves, redundant): t^T = W1^T@od^T+b1; x^T = W2^T@t^T+b2 ----
    short8v of8[2][4];
    #pragma unroll
    for (int t = 0; t < 2; ++t)
      #pragma unroll
      for (int nt = 0; nt < 4; ++nt)
        of8[t][nt] = cvt8(od[2 * t][nt], od[2 * t + 1][nt]);
    short8v tf8[2][4];
    {
      float4v ta[4][4];
      mmT8(ws + (size_t)(160 + l) * WSM, of8, b1 + l * D, 1.0f, g, lane, ta);
      #pragma unroll
      for (int t = 0; t < 2; ++t)
        #pragma unroll
        for (int nt = 0; nt < 4; ++nt)
          tf8[t][nt] = cvt8(ta[2 * t][nt], ta[2 * t + 1][nt]);
    }
    mmT8(ws + (size_t)(164 + l) * WSM, tf8, b2 + l * D, 1.0f, g, lane, xacc);

    if (l < L - 1) {
      #pragma unroll
      for (int t = 0; t < 2; ++t)
        #pragma unroll
        for (int nt = 0; nt < 4; ++nt)
          xf8[t][nt] = cvt8(xacc[2 * t][nt], xacc[2 * t + 1][nt]);
    }
  }  // layers

  // ---- pooled (wave 0 only; xacc identical across waves up to bf16 eps) ----
  if (w == 0) {
    #pragma unroll
    for (int mt = 0; mt < 4; ++mt) {
      #pragma unroll
      for (int r = 0; r < 4; ++r) {
        float sv = xacc[mt][0][r] + xacc[mt][1][r] + xacc[mt][2][r];
        if (c == 0) sv += xacc[mt][3][r];  // patch 48; 49..63 pad
        sv += __shfl_xor(sv, 1);
        sv += __shfl_xor(sv, 2);
        sv += __shfl_xor(sv, 4);
        sv += __shfl_xor(sv, 8);
        if (c == 0) CLS[16 * mt + 4 * g + r] = sv * (1.0f / 49.0f);
      }
    }
  }
  __syncthreads();

  if (tid < HID) {
    float acc = bc1[tid];
    #pragma unroll 1
    for (int d = 0; d < D; ++d) acc = fmaf(CLS[d], Wc1[d * HID + tid], acc);
    CLS[64 + tid] = acc;
  }
  __syncthreads();
  if (tid < NCLS) {
    float acc = bc2[tid];
    #pragma unroll 1
    for (int j = 0; j < HID; ++j) acc = fmaf(CLS[64 + j], Wc2[j * NCLS + tid], acc);
    CLS[96 + tid] = acc;
  }
  __syncthreads();
  if (tid == 0) {
    float mx = CLS[96];
    int am = 0;
    #pragma unroll 1
    for (int cc = 1; cc < NCLS; ++cc) {
      const float v = CLS[96 + cc];
      if (v > mx) { mx = v; am = cc; }  // strict '>' == first max (jnp.argmax)
    }
    float se = 0.0f;
    #pragma unroll 1
    for (int cc = 0; cc < NCLS; ++cc) se += expf(CLS[96 + cc] - mx);
    const float lse = mx + logf(se);
    const int lbl = labels[b];
    ws_loss[b] = lse - CLS[96 + lbl];
    ws_corr[b] = (am == lbl) ? 1.0f : 0.0f;
  }
}

__global__ void __launch_bounds__(256)
reduce_kernel(const float* __restrict__ wsl, const float* __restrict__ wsc,
              float* __restrict__ out, int n) {
  __shared__ float sl[256];
  __shared__ float sc[256];
  const int t = threadIdx.x;
  float a = 0.0f, cc = 0.0f;
  for (int idx = t; idx < n; idx += 256) { a += wsl[idx]; cc += wsc[idx]; }
  sl[t] = a; sc[t] = cc;
  __syncthreads();
  for (int s = 128; s > 0; s >>= 1) {
    if (t < s) { sl[t] += sl[t + s]; sc[t] += sc[t + s]; }
    __syncthreads();
  }
  if (t == 0) {
    out[0] = sl[0] / (float)n;
    out[1] = sc[0] / (float)n;
  }
}

}  // namespace

extern "C" void kernel_launch(void* const* d_in, const int* in_sizes, int n_in,
                              void* d_out, int out_size, void* d_ws, size_t ws_size,
                              hipStream_t stream) {
  const float* emb    = (const float*)d_in[0];
  const int*   labels = (const int*)d_in[1];
  const float* Wq   = (const float*)d_in[2];
  const float* bq   = (const float*)d_in[3];
  const float* Wk   = (const float*)d_in[4];
  const float* bk   = (const float*)d_in[5];
  const float* Wv   = (const float*)d_in[6];
  const float* bv   = (const float*)d_in[7];
  const float* Wh   = (const float*)d_in[8];
  const float* bh   = (const float*)d_in[9];
  const float* Wout = (const float*)d_in[10];
  const float* W1   = (const float*)d_in[11];
  const float* b1   = (const float*)d_in[12];
  const float* W2   = (const float*)d_in[13];
  const float* b2   = (const float*)d_in[14];
  const float* Wc1  = (const float*)d_in[15];
  const float* bc1  = (const float*)d_in[16];
  const float* Wc2  = (const float*)d_in[17];
  const float* bc2  = (const float*)d_in[18];

  const int B = in_sizes[1];  // 2048
  const size_t wBytes = (size_t)168 * WSM * sizeof(unsigned short);
  const size_t need = wBytes + (size_t)2 * B * sizeof(float);
  if (ws_size < need) return;

  unsigned short* wsb = (unsigned short*)d_ws;
  float* wsf = (float*)((char*)d_ws + wBytes);
  float* out = (float*)d_out;

  prep_weights<<<168, 256, 0, stream>>>(Wq, Wk, Wv, Wh, Wout, W1, W2, wsb);
  encoder_kernel<<<B, 128, 0, stream>>>(emb, labels, wsb, bq, bk, bv, bh,
                                        b1, b2, Wc1, bc1, Wc2, bc2,
                                        wsf, wsf + B);
  reduce_kernel<<<1, 256, 0, stream>>>(wsf, wsf + B, out, B);
}

// Round 10
// 233.665 us; speedup vs baseline: 3.7761x; 3.7761x over previous
//
#include <hip/hip_runtime.h>
#include <math.h>

namespace {

constexpr int D    = 49;
constexpr int H    = 8;
constexpr int L    = 4;
constexpr int HID  = 25;
constexpr int NCLS = 10;
constexpr int XS   = 68;    // LDS staging row stride (bf16 elems)
constexpr int WSM  = 4096;  // ushorts per padded 64x64 matrix in frag layout
// fold 1/(sqrt(49)+1e-6) * log2(e) into Wk so softmax uses exp2 directly
constexpr float SCLF  = 1.44269504088896f / (7.0f + 1e-6f);
constexpr float CLIP2 = 30.0f * 1.44269504088896f;  // clip bounds in log2 domain

typedef __attribute__((ext_vector_type(4))) short short4v;
typedef __attribute__((ext_vector_type(8))) short short8v;
typedef __attribute__((ext_vector_type(4))) float float4v;
typedef __attribute__((ext_vector_type(8))) __bf16 bf16x8;

__device__ __forceinline__ float4v mfma32(short8v a, short8v b, float4v c) {
  return __builtin_amdgcn_mfma_f32_16x16x32_bf16(a, b, c, 0, 0, 0);
}

__device__ __forceinline__ unsigned short f2bf(float x) {  // RNE
  unsigned u = __float_as_uint(x);
  return (unsigned short)((u + 0x7FFFu + ((u >> 16) & 1u)) >> 16);
}

__device__ __forceinline__ short8v cvt8(float4v lo, float4v hi) {
  bf16x8 b = {(__bf16)lo[0], (__bf16)lo[1], (__bf16)lo[2], (__bf16)lo[3],
              (__bf16)hi[0], (__bf16)hi[1], (__bf16)hi[2], (__bf16)hi[3]};
  return __builtin_bit_cast(short8v, b);
}

__device__ __forceinline__ float4v splat4(float x) {
  float4v v; v[0] = x; v[1] = x; v[2] = x; v[3] = x; return v;
}

__device__ __forceinline__ short8v wsld8(const unsigned short* __restrict__ w,
                                         int t, int nt, int lane) {
  return *reinterpret_cast<const short8v*>(w + ((t * 4 + nt) * 64 + lane) * 8);
}

// acc(cfrag of OUT^T) = W^T @ SRC   (biases live inside W via the ones-column)
__device__ __forceinline__ void mmT8(const unsigned short* __restrict__ w,
                                     const short8v (&src)[2][4],
                                     int lane, float4v (&acc)[4][4]) {
  #pragma unroll
  for (int mt = 0; mt < 4; ++mt)
    #pragma unroll
    for (int nt = 0; nt < 4; ++nt) acc[mt][nt] = splat4(0.0f);
  #pragma unroll
  for (int t = 0; t < 2; ++t) {
    short8v a[4];
    #pragma unroll
    for (int mt = 0; mt < 4; ++mt) a[mt] = wsld8(w, t, mt, lane);
    #pragma unroll
    for (int nt = 0; nt < 4; ++nt)
      #pragma unroll
      for (int mt = 0; mt < 4; ++mt)
        acc[mt][nt] = mfma32(a[mt], src[t][nt], acc[mt][nt]);
  }
}

// Pre-shuffle 49x49 f32 -> padded 64x64 bf16, K=32-native frag layout, with:
//   row 49 = bias row (so X-ones-column applies bias via the MFMA)
//   [49][49] = 1 for Wv/Wh/W1/W2 (ones-column propagation), 1/8 for Wout
//   Wk (and bk) pre-scaled by SCLF (log2-domain softmax)
__global__ void __launch_bounds__(256)
prep_weights(const float* __restrict__ Wq, const float* __restrict__ Wk,
             const float* __restrict__ Wv, const float* __restrict__ Wh,
             const float* __restrict__ Wout, const float* __restrict__ W1,
             const float* __restrict__ W2,
             const float* __restrict__ bq, const float* __restrict__ bk,
             const float* __restrict__ bv, const float* __restrict__ bh,
             const float* __restrict__ b1, const float* __restrict__ b2,
             unsigned short* __restrict__ ws) {
  const int m = blockIdx.x;  // 0..167
  const float* src;
  const float* bias;   // bias row (may be null)
  float scl = 1.0f, diag49 = 0.0f;
  if (m < 32)       { src = Wq   + (size_t)m * D * D;        bias = bq + m * D; }
  else if (m < 64)  { src = Wk   + (size_t)(m - 32) * D * D; bias = bk + (m - 32) * D; scl = SCLF; }
  else if (m < 96)  { src = Wv   + (size_t)(m - 64) * D * D; bias = bv + (m - 64) * D; diag49 = 1.0f; }
  else if (m < 128) { src = Wh   + (size_t)(m - 96) * D * D; bias = bh + (m - 96) * D; diag49 = 1.0f; }
  else if (m < 160) { src = Wout + (size_t)(m - 128) * D * D; bias = nullptr; diag49 = 0.125f; }
  else if (m < 164) { src = W1   + (size_t)(m - 160) * D * D; bias = b1 + (m - 160) * D; diag49 = 1.0f; }
  else              { src = W2   + (size_t)(m - 164) * D * D; bias = b2 + (m - 164) * D; diag49 = 1.0f; }

  const int tid = threadIdx.x;
  const int lane = tid & 63;
  const int gg = (lane >> 4) & 3, cc = lane & 15;
  #pragma unroll
  for (int i = 0; i < 2; ++i) {
    const int p = ((tid >> 6) << 1) | i;  // 0..7
    const int tt = p >> 2, nt = p & 3;
    short8v v;
    #pragma unroll
    for (int j = 0; j < 8; ++j) {
      const int k = 32 * tt + ((j < 4) ? (4 * gg + j) : (16 + 4 * gg + j - 4));
      const int n = 16 * nt + cc;
      float f = 0.0f;
      if (k < D && n < D)       f = src[k * D + n] * scl;
      else if (k == D) {        // bias row
        if (n < D)              f = bias ? bias[n] * scl : 0.0f;
        else if (n == D)        f = diag49;
      }
      v[j] = (short)f2bf(f);
    }
    *reinterpret_cast<short8v*>(ws + (size_t)m * WSM + ((tt * 4 + nt) * 64 + lane) * 8) = v;
  }
}

__global__ void __launch_bounds__(64, 2)
encoder_kernel(const float* __restrict__ emb, const int* __restrict__ labels,
               const unsigned short* __restrict__ ws,
               const float* __restrict__ Wc1, const float* __restrict__ bc1,
               const float* __restrict__ Wc2, const float* __restrict__ bc2,
               float* __restrict__ ws_loss, float* __restrict__ ws_corr) {
  __shared__ unsigned short X[64 * XS];  // embedding staging only
  __shared__ float CLS[128];

  const int b = blockIdx.x;
  const int lane = threadIdx.x;          // one wave per block
  const int g = lane >> 4, c = lane & 15;

  // ---- stage embedding (64x64 bf16; col 49 = ones-column, rest pad 0) ----
  for (int idx = lane; idx < 64 * 64; idx += 64) {
    const int r = idx >> 6, cc = idx & 63;
    float v = 0.0f;
    if (cc == D) v = 1.0f;
    else if (r < D && cc < D) v = emb[(size_t)b * (D * D) + r * D + cc];
    X[r * XS + cc] = f2bf(v);
  }
  __syncthreads();

  short8v xf8[2][4];  // operand frag of X (contraction over d)
  #pragma unroll
  for (int t = 0; t < 2; ++t)
    #pragma unroll
    for (int nt = 0; nt < 4; ++nt) {
      const int base = (16 * nt + c) * XS + 32 * t + 4 * g;
      short4v lo = *reinterpret_cast<const short4v*>(&X[base]);
      short4v hi = *reinterpret_cast<const short4v*>(&X[base + 16]);
      xf8[t][nt] = __builtin_shufflevector(lo, hi, 0, 1, 2, 3, 4, 5, 6, 7);
    }

  float4v xacc[4][4];  // cfrag(x^T)

  #pragma unroll 1
  for (int l = 0; l < L; ++l) {
    float4v od[4][4];  // cfrag(od^T) f32 accumulator across heads
    #pragma unroll
    for (int mt = 0; mt < 4; ++mt)
      #pragma unroll
      for (int nt = 0; nt < 4; ++nt) od[mt][nt] = splat4(0.0f);

    #pragma unroll 1
    for (int h = 0; h < H; ++h) {
      const int lh = l * H + h;
      const unsigned short* wq = ws + (size_t)(0   + lh) * WSM;
      const unsigned short* wk = ws + (size_t)(32  + lh) * WSM;
      const unsigned short* wv = ws + (size_t)(64  + lh) * WSM;
      const unsigned short* wh = ws + (size_t)(96  + lh) * WSM;
      const unsigned short* wo = ws + (size_t)(128 + lh) * WSM;

      // ---- K^T (pre-scaled, log2 domain) then Q^T ----
      short8v kf8[2][4], qf8[2][4];
      {
        float4v ka[4][4];
        mmT8(wk, xf8, lane, ka);
        #pragma unroll
        for (int t = 0; t < 2; ++t)
          #pragma unroll
          for (int nt = 0; nt < 4; ++nt)
            kf8[t][nt] = cvt8(ka[2 * t][nt], ka[2 * t + 1][nt]);
      }
      {
        float4v qa[4][4];
        mmT8(wq, xf8, lane, qa);
        #pragma unroll
        for (int t = 0; t < 2; ++t)
          #pragma unroll
          for (int nt = 0; nt < 4; ++nt)
            qf8[t][nt] = cvt8(qa[2 * t][nt], qa[2 * t + 1][nt]);
      }

      // ---- S^T = K @ Q^T (log2 domain) ----
      float4v s[4][4];
      #pragma unroll
      for (int mt = 0; mt < 4; ++mt)
        #pragma unroll
        for (int nt = 0; nt < 4; ++nt) s[mt][nt] = splat4(0.0f);
      #pragma unroll
      for (int t = 0; t < 2; ++t)
        #pragma unroll
        for (int nt = 0; nt < 4; ++nt)
          #pragma unroll
          for (int mt = 0; mt < 4; ++mt)
            s[mt][nt] = mfma32(kf8[t][mt], qf8[t][nt], s[mt][nt]);

      // ---- max-free softmax: clip bounds exp2; mask pad keys; no reductions ----
      // (clip to +-CLIP2 => p in [2^-43.3, 2^43.3], den < 2^49: no overflow)
      short8v pf8[2][4];
      #pragma unroll
      for (int mt = 0; mt < 4; ++mt)
        #pragma unroll
        for (int nt = 0; nt < 4; ++nt)
          #pragma unroll
          for (int r = 0; r < 4; ++r) {
            const float sv = fminf(fmaxf(s[mt][nt][r], -CLIP2), CLIP2);
            float p = exp2f(sv);
            if (mt == 3 && !(r == 0 && g == 0)) p = 0.0f;  // keys 49..63 are pad
            s[mt][nt][r] = p;
          }
      #pragma unroll
      for (int t = 0; t < 2; ++t)
        #pragma unroll
        for (int nt = 0; nt < 4; ++nt)
          pf8[t][nt] = cvt8(s[2 * t][nt], s[2 * t + 1][nt]);

      // ---- V = X @ Wv' (ones-column gives V[:,49]=1) ----
      short8v vf8[2][4];
      {
        float4v va[4][4];
        #pragma unroll
        for (int nt = 0; nt < 4; ++nt)
          #pragma unroll
          for (int mt = 0; mt < 4; ++mt) va[mt][nt] = splat4(0.0f);
        #pragma unroll
        for (int t = 0; t < 2; ++t) {
          short8v wvf[4];
          #pragma unroll
          for (int nt = 0; nt < 4; ++nt) wvf[nt] = wsld8(wv, t, nt, lane);
          #pragma unroll
          for (int nt = 0; nt < 4; ++nt)
            #pragma unroll
            for (int mt = 0; mt < 4; ++mt)
              va[mt][nt] = mfma32(xf8[t][mt], wvf[nt], va[mt][nt]);
        }
        #pragma unroll
        for (int t = 0; t < 2; ++t)
          #pragma unroll
          for (int nt = 0; nt < 4; ++nt)
            vf8[t][nt] = cvt8(va[2 * t][nt], va[2 * t + 1][nt]);
      }

      // ---- ctx~^T = V^T @ P~^T; den = row 49 (= sum_j P~) via one shfl/nt ----
      short8v cf8[2][4];
      {
        float4v ca[4][4];
        #pragma unroll
        for (int mt = 0; mt < 4; ++mt)
          #pragma unroll
          for (int nt = 0; nt < 4; ++nt) ca[mt][nt] = splat4(0.0f);
        #pragma unroll
        for (int t = 0; t < 2; ++t)
          #pragma unroll
          for (int nt = 0; nt < 4; ++nt)
            #pragma unroll
            for (int mt = 0; mt < 4; ++mt)
              ca[mt][nt] = mfma32(vf8[t][mt], pf8[t][nt], ca[mt][nt]);
        float inv_[4];
        #pragma unroll
        for (int nt = 0; nt < 4; ++nt) {
          // row 49 = (mt=3, g=0, r=1); lane c holds col q=16nt+c at g=0
          const float den = __shfl(ca[3][nt][1], c);
          inv_[nt] = 1.0f / den;  // den >= 2^-43.3 > 0 always
        }
        #pragma unroll
        for (int t = 0; t < 2; ++t)
          #pragma unroll
          for (int nt = 0; nt < 4; ++nt)
            cf8[t][nt] = cvt8(ca[2 * t][nt] * inv_[nt], ca[2 * t + 1][nt] * inv_[nt]);
      }

      // ---- ho^T = Wh'^T @ ctx^T (ones-row propagates: ho[:,49]=1) ----
      short8v hf8[2][4];
      {
        float4v ha[4][4];
        mmT8(wh, cf8, lane, ha);
        #pragma unroll
        for (int t = 0; t < 2; ++t)
          #pragma unroll
          for (int nt = 0; nt < 4; ++nt)
            hf8[t][nt] = cvt8(ha[2 * t][nt], ha[2 * t + 1][nt]);
      }

      // ---- od^T += Wout'^T @ ho^T (diag 1/8 rebuilds ones-col in od) ----
      #pragma unroll
      for (int t = 0; t < 2; ++t) {
        short8v a[4];
        #pragma unroll
        for (int mt = 0; mt < 4; ++mt) a[mt] = wsld8(wo, t, mt, lane);
        #pragma unroll
        for (int nt = 0; nt < 4; ++nt)
          #pragma unroll
          for (int mt = 0; mt < 4; ++mt)
            od[mt][nt] = mfma32(a[mt], hf8[t][nt], od[mt][nt]);
      }
    }  // heads

    // ---- MLP: t^T = W1'^T @ od^T; x^T = W2'^T @ t^T (biases in row 49) ----
    short8v of8[2][4];
    #pragma unroll
    for (int t = 0; t < 2; ++t)
      #pragma unroll
      for (int nt = 0; nt < 4; ++nt)
        of8[t][nt] = cvt8(od[2 * t][nt], od[2 * t + 1][nt]);
    short8v tf8[2][4];
    {
      float4v ta[4][4];
      mmT8(ws + (size_t)(160 + l) * WSM, of8, lane, ta);
      #pragma unroll
      for (int t = 0; t < 2; ++t)
        #pragma unroll
        for (int nt = 0; nt < 4; ++nt)
          tf8[t][nt] = cvt8(ta[2 * t][nt], ta[2 * t + 1][nt]);
    }
    mmT8(ws + (size_t)(164 + l) * WSM, tf8, lane, xacc);

    if (l < L - 1) {
      #pragma unroll
      for (int t = 0; t < 2; ++t)
        #pragma unroll
        for (int nt = 0; nt < 4; ++nt)
          xf8[t][nt] = cvt8(xacc[2 * t][nt], xacc[2 * t + 1][nt]);
    }
  }  // layers

  // ---- pooled[d] = mean over patch cols < 49 of x^T ----
  #pragma unroll
  for (int mt = 0; mt < 4; ++mt) {
    #pragma unroll
    for (int r = 0; r < 4; ++r) {
      float sv = xacc[mt][0][r] + xacc[mt][1][r] + xacc[mt][2][r];
      if (c == 0) sv += xacc[mt][3][r];  // patch 48; 49..63 pad
      sv += __shfl_xor(sv, 1);
      sv += __shfl_xor(sv, 2);
      sv += __shfl_xor(sv, 4);
      sv += __shfl_xor(sv, 8);
      if (c == 0) CLS[16 * mt + 4 * g + r] = sv * (1.0f / 49.0f);
    }
  }
  __syncthreads();

  // ---- classifier head (f32 scalar path; biases here are real adds) ----
  if (lane < HID) {
    float acc = bc1[lane];
    #pragma unroll 1
    for (int d = 0; d < D; ++d) acc = fmaf(CLS[d], Wc1[d * HID + lane], acc);
    CLS[64 + lane] = acc;
  }
  __syncthreads();
  if (lane < NCLS) {
    float acc = bc2[lane];
    #pragma unroll 1
    for (int j = 0; j < HID; ++j) acc = fmaf(CLS[64 + j], Wc2[j * NCLS + lane], acc);
    CLS[96 + lane] = acc;
  }
  __syncthreads();
  if (lane == 0) {
    float mx = CLS[96];
    int am = 0;
    #pragma unroll 1
    for (int cc = 1; cc < NCLS; ++cc) {
      const float v = CLS[96 + cc];
      if (v > mx) { mx = v; am = cc; }  // strict '>' == first max (jnp.argmax)
    }
    float se = 0.0f;
    #pragma unroll 1
    for (int cc = 0; cc < NCLS; ++cc) se += expf(CLS[96 + cc] - mx);
    const float lse = mx + logf(se);
    const int lbl = labels[b];
    ws_loss[b] = lse - CLS[96 + lbl];
    ws_corr[b] = (am == lbl) ? 1.0f : 0.0f;
  }
}

__global__ void __launch_bounds__(256)
reduce_kernel(const float* __restrict__ wsl, const float* __restrict__ wsc,
              float* __restrict__ out, int n) {
  __shared__ float sl[256];
  __shared__ float sc[256];
  const int t = threadIdx.x;
  float a = 0.0f, cc = 0.0f;
  for (int idx = t; idx < n; idx += 256) { a += wsl[idx]; cc += wsc[idx]; }
  sl[t] = a; sc[t] = cc;
  __syncthreads();
  for (int s = 128; s > 0; s >>= 1) {
    if (t < s) { sl[t] += sl[t + s]; sc[t] += sc[t + s]; }
    __syncthreads();
  }
  if (t == 0) {
    out[0] = sl[0] / (float)n;
    out[1] = sc[0] / (float)n;
  }
}

}  // namespace

extern "C" void kernel_launch(void* const* d_in, const int* in_sizes, int n_in,
                              void* d_out, int out_size, void* d_ws, size_t ws_size,
                              hipStream_t stream) {
  const float* emb    = (const float*)d_in[0];
  const int*   labels = (const int*)d_in[1];
  const float* Wq   = (const float*)d_in[2];
  const float* bq   = (const float*)d_in[3];
  const float* Wk   = (const float*)d_in[4];
  const float* bk   = (const float*)d_in[5];
  const float* Wv   = (const float*)d_in[6];
  const float* bv   = (const float*)d_in[7];
  const float* Wh   = (const float*)d_in[8];
  const float* bh   = (const float*)d_in[9];
  const float* Wout = (const float*)d_in[10];
  const float* W1   = (const float*)d_in[11];
  const float* b1   = (const float*)d_in[12];
  const float* W2   = (const float*)d_in[13];
  const float* b2   = (const float*)d_in[14];
  const float* Wc1  = (const float*)d_in[15];
  const float* bc1  = (const float*)d_in[16];
  const float* Wc2  = (const float*)d_in[17];
  const float* bc2  = (const float*)d_in[18];

  const int B = in_sizes[1];  // 2048
  const size_t wBytes = (size_t)168 * WSM * sizeof(unsigned short);
  const size_t need = wBytes + (size_t)2 * B * sizeof(float);
  if (ws_size < need) return;

  unsigned short* wsb = (unsigned short*)d_ws;
  float* wsf = (float*)((char*)d_ws + wBytes);
  float* out = (float*)d_out;

  prep_weights<<<168, 256, 0, stream>>>(Wq, Wk, Wv, Wh, Wout, W1, W2,
                                        bq, bk, bv, bh, b1, b2, wsb);
  encoder_kernel<<<B, 64, 0, stream>>>(emb, labels, wsb, Wc1, bc1, Wc2, bc2,
                                       wsf, wsf + B);
  reduce_kernel<<<1, 256, 0, stream>>>(wsf, wsf + B, out, B);
}

// Round 11
// 212.882 us; speedup vs baseline: 4.1448x; 1.0976x over previous
//
#include <hip/hip_runtime.h>
#include <math.h>

namespace {

constexpr int D    = 49;
constexpr int H    = 8;
constexpr int L    = 4;
constexpr int HID  = 25;
constexpr int NCLS = 10;
constexpr int XS   = 68;    // LDS staging row stride (bf16 elems)
constexpr int WSM  = 4096;  // ushorts per padded 64x64 matrix in frag layout
// fold 1/(sqrt(49)+1e-6) * log2(e) into Wk so softmax uses exp2 directly
constexpr float SCLF  = 1.44269504088896f / (7.0f + 1e-6f);
constexpr float CLIP2 = 30.0f * 1.44269504088896f;  // clip bounds in log2 domain

typedef __attribute__((ext_vector_type(4))) short short4v;
typedef __attribute__((ext_vector_type(8))) short short8v;
typedef __attribute__((ext_vector_type(4))) float float4v;
typedef __attribute__((ext_vector_type(8))) __bf16 bf16x8;

__device__ __forceinline__ float4v mfma32(short8v a, short8v b, float4v c) {
  return __builtin_amdgcn_mfma_f32_16x16x32_bf16(a, b, c, 0, 0, 0);
}

__device__ __forceinline__ unsigned short f2bf(float x) {  // RNE
  unsigned u = __float_as_uint(x);
  return (unsigned short)((u + 0x7FFFu + ((u >> 16) & 1u)) >> 16);
}

__device__ __forceinline__ short8v cvt8(float4v lo, float4v hi) {
  bf16x8 b = {(__bf16)lo[0], (__bf16)lo[1], (__bf16)lo[2], (__bf16)lo[3],
              (__bf16)hi[0], (__bf16)hi[1], (__bf16)hi[2], (__bf16)hi[3]};
  return __builtin_bit_cast(short8v, b);
}

__device__ __forceinline__ float exp2_hw(float x) {  // x bounded by clip: safe
  float r;
  asm("v_exp_f32 %0, %1" : "=v"(r) : "v"(x));
  return r;
}

__device__ __forceinline__ float4v splat4(float x) {
  float4v v; v[0] = x; v[1] = x; v[2] = x; v[3] = x; return v;
}

__device__ __forceinline__ short8v wsld8(const unsigned short* __restrict__ w,
                                         int t, int nt, int lane) {
  return *reinterpret_cast<const short8v*>(w + ((t * 4 + nt) * 64 + lane) * 8);
}

// acc(cfrag of OUT^T) = W^T @ SRC   (biases live inside W via the ones-column)
__device__ __forceinline__ void mmT8(const unsigned short* __restrict__ w,
                                     const short8v (&src)[2][4],
                                     int lane, float4v (&acc)[4][4]) {
  #pragma unroll
  for (int mt = 0; mt < 4; ++mt)
    #pragma unroll
    for (int nt = 0; nt < 4; ++nt) acc[mt][nt] = splat4(0.0f);
  #pragma unroll
  for (int t = 0; t < 2; ++t) {
    short8v a[4];
    #pragma unroll
    for (int mt = 0; mt < 4; ++mt) a[mt] = wsld8(w, t, mt, lane);
    #pragma unroll
    for (int nt = 0; nt < 4; ++nt)
      #pragma unroll
      for (int mt = 0; mt < 4; ++mt)
        acc[mt][nt] = mfma32(a[mt], src[t][nt], acc[mt][nt]);
  }
}

// Pre-shuffle 49x49 f32 -> padded 64x64 bf16, K=32-native frag layout, with:
//   row 49 = bias row (so X-ones-column applies bias via the MFMA)
//   [49][49] = 1 for Wv/Wh/W1/W2 (ones-column propagation), 1/8 for Wout
//   Wk (and bk) pre-scaled by SCLF (log2-domain softmax)
__global__ void __launch_bounds__(256)
prep_weights(const float* __restrict__ Wq, const float* __restrict__ Wk,
             const float* __restrict__ Wv, const float* __restrict__ Wh,
             const float* __restrict__ Wout, const float* __restrict__ W1,
             const float* __restrict__ W2,
             const float* __restrict__ bq, const float* __restrict__ bk,
             const float* __restrict__ bv, const float* __restrict__ bh,
             const float* __restrict__ b1, const float* __restrict__ b2,
             unsigned short* __restrict__ ws) {
  const int m = blockIdx.x;  // 0..167
  const float* src;
  const float* bias;   // bias row (may be null)
  float scl = 1.0f, diag49 = 0.0f;
  if (m < 32)       { src = Wq   + (size_t)m * D * D;        bias = bq + m * D; }
  else if (m < 64)  { src = Wk   + (size_t)(m - 32) * D * D; bias = bk + (m - 32) * D; scl = SCLF; }
  else if (m < 96)  { src = Wv   + (size_t)(m - 64) * D * D; bias = bv + (m - 64) * D; diag49 = 1.0f; }
  else if (m < 128) { src = Wh   + (size_t)(m - 96) * D * D; bias = bh + (m - 96) * D; diag49 = 1.0f; }
  else if (m < 160) { src = Wout + (size_t)(m - 128) * D * D; bias = nullptr; diag49 = 0.125f; }
  else if (m < 164) { src = W1   + (size_t)(m - 160) * D * D; bias = b1 + (m - 160) * D; diag49 = 1.0f; }
  else              { src = W2   + (size_t)(m - 164) * D * D; bias = b2 + (m - 164) * D; diag49 = 1.0f; }

  const int tid = threadIdx.x;
  const int lane = tid & 63;
  const int gg = (lane >> 4) & 3, cc = lane & 15;
  #pragma unroll
  for (int i = 0; i < 2; ++i) {
    const int p = ((tid >> 6) << 1) | i;  // 0..7
    const int tt = p >> 2, nt = p & 3;
    short8v v;
    #pragma unroll
    for (int j = 0; j < 8; ++j) {
      const int k = 32 * tt + ((j < 4) ? (4 * gg + j) : (16 + 4 * gg + j - 4));
      const int n = 16 * nt + cc;
      float f = 0.0f;
      if (k < D && n < D)       f = src[k * D + n] * scl;
      else if (k == D) {        // bias row
        if (n < D)              f = bias ? bias[n] * scl : 0.0f;
        else if (n == D)        f = diag49;
      }
      v[j] = (short)f2bf(f);
    }
    *reinterpret_cast<short8v*>(ws + (size_t)m * WSM + ((tt * 4 + nt) * 64 + lane) * 8) = v;
  }
}

__global__ void __launch_bounds__(64, 2)
encoder_kernel(const float* __restrict__ emb, const int* __restrict__ labels,
               const unsigned short* __restrict__ ws,
               const float* __restrict__ Wc1, const float* __restrict__ bc1,
               const float* __restrict__ Wc2, const float* __restrict__ bc2,
               float* __restrict__ ws_loss, float* __restrict__ ws_corr) {
  __shared__ unsigned short X[64 * XS];  // embedding staging only
  __shared__ float CLS[128];

  const int b = blockIdx.x;
  const int lane = threadIdx.x;          // one wave per block
  const int g = lane >> 4, c = lane & 15;

  // ---- stage embedding (64x64 bf16; col 49 = ones-column, rest pad 0) ----
  for (int idx = lane; idx < 64 * 64; idx += 64) {
    const int r = idx >> 6, cc = idx & 63;
    float v = 0.0f;
    if (cc == D) v = 1.0f;
    else if (r < D && cc < D) v = emb[(size_t)b * (D * D) + r * D + cc];
    X[r * XS + cc] = f2bf(v);
  }
  __syncthreads();

  short8v xf8[2][4];  // operand frag of X (contraction over d)
  #pragma unroll
  for (int t = 0; t < 2; ++t)
    #pragma unroll
    for (int nt = 0; nt < 4; ++nt) {
      const int base = (16 * nt + c) * XS + 32 * t + 4 * g;
      short4v lo = *reinterpret_cast<const short4v*>(&X[base]);
      short4v hi = *reinterpret_cast<const short4v*>(&X[base + 16]);
      xf8[t][nt] = __builtin_shufflevector(lo, hi, 0, 1, 2, 3, 4, 5, 6, 7);
    }

  float4v xacc[4][4];  // cfrag(x^T)

  #pragma unroll 1
  for (int l = 0; l < L; ++l) {
    float4v od[4][4];  // cfrag(od^T) f32 accumulator across heads
    #pragma unroll
    for (int mt = 0; mt < 4; ++mt)
      #pragma unroll
      for (int nt = 0; nt < 4; ++nt) od[mt][nt] = splat4(0.0f);

    // unroll 2: head h+1's K/Q/V matmuls are independent of head h's
    // softmax/PV/ho tail -> compiler interleaves to fill both pipes.
    #pragma unroll 2
    for (int h = 0; h < H; ++h) {
      const int lh = l * H + h;
      const unsigned short* wq = ws + (size_t)(0   + lh) * WSM;
      const unsigned short* wk = ws + (size_t)(32  + lh) * WSM;
      const unsigned short* wv = ws + (size_t)(64  + lh) * WSM;
      const unsigned short* wh = ws + (size_t)(96  + lh) * WSM;
      const unsigned short* wo = ws + (size_t)(128 + lh) * WSM;

      // ---- K^T (pre-scaled, log2 domain) then Q^T ----
      short8v kf8[2][4], qf8[2][4];
      {
        float4v ka[4][4];
        mmT8(wk, xf8, lane, ka);
        #pragma unroll
        for (int t = 0; t < 2; ++t)
          #pragma unroll
          for (int nt = 0; nt < 4; ++nt)
            kf8[t][nt] = cvt8(ka[2 * t][nt], ka[2 * t + 1][nt]);
      }
      {
        float4v qa[4][4];
        mmT8(wq, xf8, lane, qa);
        #pragma unroll
        for (int t = 0; t < 2; ++t)
          #pragma unroll
          for (int nt = 0; nt < 4; ++nt)
            qf8[t][nt] = cvt8(qa[2 * t][nt], qa[2 * t + 1][nt]);
      }

      // ---- S^T = K @ Q^T (log2 domain) ----
      float4v s[4][4];
      #pragma unroll
      for (int mt = 0; mt < 4; ++mt)
        #pragma unroll
        for (int nt = 0; nt < 4; ++nt) s[mt][nt] = splat4(0.0f);
      #pragma unroll
      for (int t = 0; t < 2; ++t)
        #pragma unroll
        for (int nt = 0; nt < 4; ++nt)
          #pragma unroll
          for (int mt = 0; mt < 4; ++mt)
            s[mt][nt] = mfma32(kf8[t][mt], qf8[t][nt], s[mt][nt]);

      // ---- max-free softmax: clip bounds exp2; pad keys masked at
      //      compile time (key j = 16mt+4g+r: mt==3 && r>0 always pad;
      //      mt==3,r==0 pad unless g==0). No cross-lane reductions. ----
      short8v pf8[2][4];
      #pragma unroll
      for (int mt = 0; mt < 4; ++mt)
        #pragma unroll
        for (int nt = 0; nt < 4; ++nt)
          #pragma unroll
          for (int r = 0; r < 4; ++r) {
            if (mt == 3 && r > 0) { s[mt][nt][r] = 0.0f; continue; }
            const float sv = fminf(fmaxf(s[mt][nt][r], -CLIP2), CLIP2);
            float p = exp2_hw(sv);
            if (mt == 3) p = (g == 0) ? p : 0.0f;  // r==0: key 48+4g
            s[mt][nt][r] = p;
          }
      #pragma unroll
      for (int t = 0; t < 2; ++t)
        #pragma unroll
        for (int nt = 0; nt < 4; ++nt)
          pf8[t][nt] = cvt8(s[2 * t][nt], s[2 * t + 1][nt]);

      // ---- V = X @ Wv' (ones-column gives V[:,49]=1) ----
      short8v vf8[2][4];
      {
        float4v va[4][4];
        #pragma unroll
        for (int nt = 0; nt < 4; ++nt)
          #pragma unroll
          for (int mt = 0; mt < 4; ++mt) va[mt][nt] = splat4(0.0f);
        #pragma unroll
        for (int t = 0; t < 2; ++t) {
          short8v wvf[4];
          #pragma unroll
          for (int nt = 0; nt < 4; ++nt) wvf[nt] = wsld8(wv, t, nt, lane);
          #pragma unroll
          for (int nt = 0; nt < 4; ++nt)
            #pragma unroll
            for (int mt = 0; mt < 4; ++mt)
              va[mt][nt] = mfma32(xf8[t][mt], wvf[nt], va[mt][nt]);
        }
        #pragma unroll
        for (int t = 0; t < 2; ++t)
          #pragma unroll
          for (int nt = 0; nt < 4; ++nt)
            vf8[t][nt] = cvt8(va[2 * t][nt], va[2 * t + 1][nt]);
      }

      // ---- ctx~^T = V^T @ P~^T; den = row 49 (= sum_j P~) via one shfl/nt ----
      short8v cf8[2][4];
      {
        float4v ca[4][4];
        #pragma unroll
        for (int mt = 0; mt < 4; ++mt)
          #pragma unroll
          for (int nt = 0; nt < 4; ++nt) ca[mt][nt] = splat4(0.0f);
        #pragma unroll
        for (int t = 0; t < 2; ++t)
          #pragma unroll
          for (int nt = 0; nt < 4; ++nt)
            #pragma unroll
            for (int mt = 0; mt < 4; ++mt)
              ca[mt][nt] = mfma32(vf8[t][mt], pf8[t][nt], ca[mt][nt]);
        float inv_[4];
        #pragma unroll
        for (int nt = 0; nt < 4; ++nt) {
          // row 49 = (mt=3, g=0, r=1); lane c holds col q=16nt+c at g=0
          const float den = __shfl(ca[3][nt][1], c);
          inv_[nt] = 1.0f / den;  // den >= 2^-43.3 > 0 always
        }
        #pragma unroll
        for (int t = 0; t < 2; ++t)
          #pragma unroll
          for (int nt = 0; nt < 4; ++nt)
            cf8[t][nt] = cvt8(ca[2 * t][nt] * inv_[nt], ca[2 * t + 1][nt] * inv_[nt]);
      }

      // ---- ho^T = Wh'^T @ ctx^T (ones-row propagates: ho[:,49]=1) ----
      short8v hf8[2][4];
      {
        float4v ha[4][4];
        mmT8(wh, cf8, lane, ha);
        #pragma unroll
        for (int t = 0; t < 2; ++t)
          #pragma unroll
          for (int nt = 0; nt < 4; ++nt)
            hf8[t][nt] = cvt8(ha[2 * t][nt], ha[2 * t + 1][nt]);
      }

      // ---- od^T += Wout'^T @ ho^T (diag 1/8 rebuilds ones-col in od) ----
      #pragma unroll
      for (int t = 0; t < 2; ++t) {
        short8v a[4];
        #pragma unroll
        for (int mt = 0; mt < 4; ++mt) a[mt] = wsld8(wo, t, mt, lane);
        #pragma unroll
        for (int nt = 0; nt < 4; ++nt)
          #pragma unroll
          for (int mt = 0; mt < 4; ++mt)
            od[mt][nt] = mfma32(a[mt], hf8[t][nt], od[mt][nt]);
      }
    }  // heads

    // ---- MLP: t^T = W1'^T @ od^T; x^T = W2'^T @ t^T (biases in row 49) ----
    short8v of8[2][4];
    #pragma unroll
    for (int t = 0; t < 2; ++t)
      #pragma unroll
      for (int nt = 0; nt < 4; ++nt)
        of8[t][nt] = cvt8(od[2 * t][nt], od[2 * t + 1][nt]);
    short8v tf8[2][4];
    {
      float4v ta[4][4];
      mmT8(ws + (size_t)(160 + l) * WSM, of8, lane, ta);
      #pragma unroll
      for (int t = 0; t < 2; ++t)
        #pragma unroll
        for (int nt = 0; nt < 4; ++nt)
          tf8[t][nt] = cvt8(ta[2 * t][nt], ta[2 * t + 1][nt]);
    }
    mmT8(ws + (size_t)(164 + l) * WSM, tf8, lane, xacc);

    if (l < L - 1) {
      #pragma unroll
      for (int t = 0; t < 2; ++t)
        #pragma unroll
        for (int nt = 0; nt < 4; ++nt)
          xf8[t][nt] = cvt8(xacc[2 * t][nt], xacc[2 * t + 1][nt]);
    }
  }  // layers

  // ---- pooled[d] = mean over patch cols < 49 of x^T ----
  #pragma unroll
  for (int mt = 0; mt < 4; ++mt) {
    #pragma unroll
    for (int r = 0; r < 4; ++r) {
      float sv = xacc[mt][0][r] + xacc[mt][1][r] + xacc[mt][2][r];
      if (c == 0) sv += xacc[mt][3][r];  // patch 48; 49..63 pad
      sv += __shfl_xor(sv, 1);
      sv += __shfl_xor(sv, 2);
      sv += __shfl_xor(sv, 4);
      sv += __shfl_xor(sv, 8);
      if (c == 0) CLS[16 * mt + 4 * g + r] = sv * (1.0f / 49.0f);
    }
  }
  __syncthreads();

  // ---- classifier head (f32 scalar path; biases here are real adds) ----
  if (lane < HID) {
    float acc = bc1[lane];
    #pragma unroll 1
    for (int d = 0; d < D; ++d) acc = fmaf(CLS[d], Wc1[d * HID + lane], acc);
    CLS[64 + lane] = acc;
  }
  __syncthreads();
  if (lane < NCLS) {
    float acc = bc2[lane];
    #pragma unroll 1
    for (int j = 0; j < HID; ++j) acc = fmaf(CLS[64 + j], Wc2[j * NCLS + lane], acc);
    CLS[96 + lane] = acc;
  }
  __syncthreads();
  if (lane == 0) {
    float mx = CLS[96];
    int am = 0;
    #pragma unroll 1
    for (int cc = 1; cc < NCLS; ++cc) {
      const float v = CLS[96 + cc];
      if (v > mx) { mx = v; am = cc; }  // strict '>' == first max (jnp.argmax)
    }
    float se = 0.0f;
    #pragma unroll 1
    for (int cc = 0; cc < NCLS; ++cc) se += expf(CLS[96 + cc] - mx);
    const float lse = mx + logf(se);
    const int lbl = labels[b];
    ws_loss[b] = lse - CLS[96 + lbl];
    ws_corr[b] = (am == lbl) ? 1.0f : 0.0f;
  }
}

__global__ void __launch_bounds__(256)
reduce_kernel(const float* __restrict__ wsl, const float* __restrict__ wsc,
              float* __restrict__ out, int n) {
  __shared__ float sl[256];
  __shared__ float sc[256];
  const int t = threadIdx.x;
  float a = 0.0f, cc = 0.0f;
  for (int idx = t; idx < n; idx += 256) { a += wsl[idx]; cc += wsc[idx]; }
  sl[t] = a; sc[t] = cc;
  __syncthreads();
  for (int s = 128; s > 0; s >>= 1) {
    if (t < s) { sl[t] += sl[t + s]; sc[t] += sc[t + s]; }
    __syncthreads();
  }
  if (t == 0) {
    out[0] = sl[0] / (float)n;
    out[1] = sc[0] / (float)n;
  }
}

}  // namespace

extern "C" void kernel_launch(void* const* d_in, const int* in_sizes, int n_in,
                              void* d_out, int out_size, void* d_ws, size_t ws_size,
                              hipStream_t stream) {
  const float* emb    = (const float*)d_in[0];
  const int*   labels = (const int*)d_in[1];
  const float* Wq   = (const float*)d_in[2];
  const float* bq   = (const float*)d_in[3];
  const float* Wk   = (const float*)d_in[4];
  const float* bk   = (const float*)d_in[5];
  const float* Wv   = (const float*)d_in[6];
  const float* bv   = (const float*)d_in[7];
  const float* Wh   = (const float*)d_in[8];
  const float* bh   = (const float*)d_in[9];
  const float* Wout = (const float*)d_in[10];
  const float* W1   = (const float*)d_in[11];
  const float* b1   = (const float*)d_in[12];
  const float* W2   = (const float*)d_in[13];
  const float* b2   = (const float*)d_in[14];
  const float* Wc1  = (const float*)d_in[15];
  const float* bc1  = (const float*)d_in[16];
  const float* Wc2  = (const float*)d_in[17];
  const float* bc2  = (const float*)d_in[18];

  const int B = in_sizes[1];  // 2048
  const size_t wBytes = (size_t)168 * WSM * sizeof(unsigned short);
  const size_t need = wBytes + (size_t)2 * B * sizeof(float);
  if (ws_size < need) return;

  unsigned short* wsb = (unsigned short*)d_ws;
  float* wsf = (float*)((char*)d_ws + wBytes);
  float* out = (float*)d_out;

  prep_weights<<<168, 256, 0, stream>>>(Wq, Wk, Wv, Wh, Wout, W1, W2,
                                        bq, bk, bv, bh, b1, b2, wsb);
  encoder_kernel<<<B, 64, 0, stream>>>(emb, labels, wsb, Wc1, bc1, Wc2, bc2,
                                       wsf, wsf + B);
  reduce_kernel<<<1, 256, 0, stream>>>(wsf, wsf + B, out, B);
}